// Round 6
// baseline (1040.492 us; speedup 1.0000x reference)
//
#include <hip/hip_runtime.h>
#include <hip/hip_fp16.h>

#define LEAKY_SLOPE 0.01f
#define LN_EPS 1e-6f
#define CAP 9216          // per coarse-bucket slab slots (mean 8192, +11 sigma)
#define BATCH 2048        // edges per sort block

__device__ __forceinline__ float head_sel(int h, float a, float b, float c, float d) {
    float lo = (h & 1) ? b : a;
    float hi = (h & 1) ? d : c;
    return (h & 2) ? hi : lo;
}

// ---------------------------------------------------------------------------
// K1: node projection. One wave per node. Writes Wn as fp16 (halves gather
// traffic downstream), plus s_s/s_r/lm_self scalars.
// ---------------------------------------------------------------------------
__global__ __launch_bounds__(256) void node_proj_kernel(
    const float* __restrict__ nodes, const float* __restrict__ W,
    const float* __restrict__ a, __half* __restrict__ Wn_h,
    float* __restrict__ s_s, float* __restrict__ s_r,
    float* __restrict__ lm_self, int N)
{
    __shared__ float Wt[64][65];   // transposed, +1 pad: Wt[i][o] = W[o*64+i]
    int t = threadIdx.x;
    #pragma unroll
    for (int k = 0; k < 16; k++) {
        int flat = k * 256 + t;
        Wt[flat & 63][flat >> 6] = W[flat];
    }
    __syncthreads();
    int lane = t & 63;
    int n = blockIdx.x * 4 + (t >> 6);
    if (n >= N) return;
    float nv = nodes[(size_t)n * 64 + lane];
    float acc = 0.f;
    #pragma unroll
    for (int i = 0; i < 64; i++)
        acc += Wt[i][lane] * __shfl(nv, i);
    Wn_h[(size_t)n * 64 + lane] = __float2half(acc);
    int h = lane >> 4, f = lane & 15;
    float ps = acc * a[h * 48 + f];
    float pr = acc * a[h * 48 + 16 + f];
    #pragma unroll
    for (int off = 1; off < 16; off <<= 1) {
        ps += __shfl_xor(ps, off);
        pr += __shfl_xor(pr, off);
    }
    if (f == 0) {
        s_s[n * 4 + h] = ps;
        s_r[n * 4 + h] = pr;
        float v = ps + pr;
        lm_self[n * 4 + h] = v > 0.f ? v : LEAKY_SLOPE * v;
    }
}

// ---------------------------------------------------------------------------
// K2: per-block (2048 edges) logits + in-LDS counting sort by coarse bucket
// (cb = receiver >> 8, 256 nodes per bucket). Each bucket's run is appended
// contiguously to the bucket's slab region (ONE global atomic per run, all
// payload writes coalesced -> no scattered-line RMW).
// Payload 16B: {lm0 f32, lm1 f32, (lm2 h|lm3 h<<16), (sender u16 | rloc u8<<16)}
// ---------------------------------------------------------------------------
__global__ __launch_bounds__(256) void edge_sort_kernel(
    const float* __restrict__ edges, const int* __restrict__ receivers,
    const int* __restrict__ senders, const float* __restrict__ W_edge,
    const float* __restrict__ a, const float* __restrict__ s_s,
    const float* __restrict__ s_r, int* __restrict__ gcursor,
    int4* __restrict__ slab, int E)
{
    __shared__ float be[4][16];              // be[h][i] = sum_f W_edge[h,f,i]*a_e[h,f]
    __shared__ int4 raw[BATCH];              // 32 KB
    __shared__ unsigned perm[BATCH];         // 8 KB: (cb<<16 | local idx)
    __shared__ unsigned char cbarr[BATCH];   // 2 KB
    __shared__ int hist[256];
    __shared__ int sc[256];
    __shared__ int loff[256];
    __shared__ int cur[256];
    __shared__ int gbase[256];

    int t = threadIdx.x;
    hist[t] = 0;
    if (t < 64) {
        int h = t >> 4, i = t & 15;
        float s = 0.f;
        #pragma unroll
        for (int f = 0; f < 16; f++)
            s += W_edge[(h * 16 + f) * 16 + i] * a[h * 48 + 32 + f];
        be[h][i] = s;
    }
    __syncthreads();

    int base_e = blockIdx.x * BATCH;
    int cnt = min(BATCH, E - base_e);

    // phase 1: compute payloads into LDS + histogram coarse buckets
    #pragma unroll
    for (int k = 0; k < BATCH / 256; k++) {
        int i = k * 256 + t;
        if (i < cnt) {
            int e = base_e + i;
            int r = receivers[e], s = senders[e];
            const float4* ef = (const float4*)(edges + (size_t)e * 16);
            float4 e0 = ef[0], e1 = ef[1], e2 = ef[2], e3 = ef[3];
            float4 ssv = ((const float4*)s_s)[s];
            float4 srv = ((const float4*)s_r)[r];
            float ev[16] = {e0.x, e0.y, e0.z, e0.w, e1.x, e1.y, e1.z, e1.w,
                            e2.x, e2.y, e2.z, e2.w, e3.x, e3.y, e3.z, e3.w};
            float ssa[4] = {ssv.x, ssv.y, ssv.z, ssv.w};
            float sra[4] = {srv.x, srv.y, srv.z, srv.w};
            float lm[4];
            #pragma unroll
            for (int hh = 0; hh < 4; hh++) {
                float se = 0.f;
                #pragma unroll
                for (int ii = 0; ii < 16; ii++) se += be[hh][ii] * ev[ii];
                float v = ssa[hh] + sra[hh] + se;
                lm[hh] = v > 0.f ? v : LEAKY_SLOPE * v;
            }
            int cb = r >> 8;
            unsigned packA = (unsigned)__half_as_ushort(__float2half(lm[2])) |
                             ((unsigned)__half_as_ushort(__float2half(lm[3])) << 16);
            unsigned packB = (unsigned)s | ((unsigned)(r & 255) << 16);
            raw[i] = make_int4(__float_as_int(lm[0]), __float_as_int(lm[1]),
                               (int)packA, (int)packB);
            cbarr[i] = (unsigned char)cb;
            atomicAdd(&hist[cb], 1);
        }
    }
    __syncthreads();

    // phase 2: block-wide exclusive scan of hist (256-wide Hillis-Steele)
    sc[t] = hist[t];
    __syncthreads();
    for (int off = 1; off < 256; off <<= 1) {
        int u = (t >= off) ? sc[t - off] : 0;
        __syncthreads();
        sc[t] += u;
        __syncthreads();
    }
    int lo = sc[t] - hist[t];
    loff[t] = lo;
    cur[t] = lo;
    if (hist[t] > 0) gbase[t] = atomicAdd(&gcursor[t], hist[t]);
    __syncthreads();

    // phase 3: build permutation (sorted order by coarse bucket)
    #pragma unroll
    for (int k = 0; k < BATCH / 256; k++) {
        int i = k * 256 + t;
        if (i < cnt) {
            int cb = cbarr[i];
            int pos = atomicAdd(&cur[cb], 1);
            perm[pos] = ((unsigned)cb << 16) | (unsigned)i;
        }
    }
    __syncthreads();

    // phase 4: coalesced run write-out
    for (int pos = t; pos < cnt; pos += 256) {
        unsigned u = perm[pos];
        int cb = (int)(u >> 16);
        int idx = (int)(u & 0xFFFFu);
        int slot = gbase[cb] + (pos - loff[cb]);
        if (slot < CAP)
            slab[(size_t)cb * CAP + slot] = raw[idx];
    }
}

// ---------------------------------------------------------------------------
// K3: per-coarse-bucket accumulation. One block per 256 nodes. LDS fp32
// accumulator acc[256][65] (stride 65 randomizes banks) + denominators.
// Each thread consumes one edge: 4 exps, 4 denom ds_adds, 128 B fp16 Wn
// gather, 64 fma + ds_add. Fused epilogue: /denom, +self, ELU, LayerNorm.
// ---------------------------------------------------------------------------
__global__ __launch_bounds__(256) void bucket_accum_kernel(
    const __half* __restrict__ Wn_h, const float* __restrict__ lm_self,
    const int* __restrict__ gcursor, const int4* __restrict__ slab,
    const float* __restrict__ ln_scale, const float* __restrict__ ln_bias,
    float* __restrict__ out, int N)
{
    __shared__ float acc[256][65];     // 66.6 KB
    __shared__ float denom[256][4];    // 4 KB

    int cb = blockIdx.x;
    int t = threadIdx.x;
    int lane = t & 63;
    int nb = min(256, N - cb * 256);

    for (int i = t; i < 256 * 65; i += 256) ((float*)acc)[i] = 0.f;
    for (int i = t; i < 256 * 4; i += 256) ((float*)denom)[i] = 0.f;
    __syncthreads();

    int cnt = min(gcursor[cb], CAP);
    const int4* src = slab + (size_t)cb * CAP;

    for (int i = t; i < cnt; i += 256) {
        int4 p = src[i];
        float w0 = __expf(__int_as_float(p.x));
        float w1 = __expf(__int_as_float(p.y));
        unsigned pa = (unsigned)p.z;
        float w2 = __expf(__half2float(__ushort_as_half((unsigned short)(pa & 0xFFFFu))));
        float w3 = __expf(__half2float(__ushort_as_half((unsigned short)(pa >> 16))));
        unsigned pb = (unsigned)p.w;
        int s  = (int)(pb & 0xFFFFu);
        int rl = (int)((pb >> 16) & 0xFFu);
        atomicAdd(&denom[rl][0], w0);
        atomicAdd(&denom[rl][1], w1);
        atomicAdd(&denom[rl][2], w2);
        atomicAdd(&denom[rl][3], w3);
        float wh[4] = {w0, w1, w2, w3};
        const uint4* wp4 = (const uint4*)(Wn_h + (size_t)s * 64);
        #pragma unroll
        for (int j = 0; j < 8; j++) {       // 8 features x 8 halfs
            uint4 v4 = wp4[j];
            float ww = wh[j >> 1];
            float* arow = &acc[rl][j * 8];
            float2 f0 = __half22float2(*(const __half2*)&v4.x);
            float2 f1 = __half22float2(*(const __half2*)&v4.y);
            float2 f2 = __half22float2(*(const __half2*)&v4.z);
            float2 f3 = __half22float2(*(const __half2*)&v4.w);
            atomicAdd(&arow[0], ww * f0.x);
            atomicAdd(&arow[1], ww * f0.y);
            atomicAdd(&arow[2], ww * f1.x);
            atomicAdd(&arow[3], ww * f1.y);
            atomicAdd(&arow[4], ww * f2.x);
            atomicAdd(&arow[5], ww * f2.y);
            atomicAdd(&arow[6], ww * f3.x);
            atomicAdd(&arow[7], ww * f3.y);
        }
    }
    __syncthreads();

    // epilogue: 4 waves iterate nodes; lane = feature
    int wv = t >> 6;
    int h = lane >> 4;
    for (int nl = wv; nl < nb; nl += 4) {
        int n = cb * 256 + nl;
        float4 ls = ((const float4*)lm_self)[n];
        float ws0 = __expf(ls.x), ws1 = __expf(ls.y);
        float ws2 = __expf(ls.z), ws3 = __expf(ls.w);
        float wself = head_sel(h, ws0, ws1, ws2, ws3);
        float dtot  = head_sel(h, denom[nl][0] + ws0, denom[nl][1] + ws1,
                                  denom[nl][2] + ws2, denom[nl][3] + ws3);
        float selfv = __half2float(Wn_h[(size_t)n * 64 + lane]);
        float av = (acc[nl][lane] + wself * selfv) / dtot;

        float y = av > 0.f ? av : expm1f(av);
        float sum = y;
        #pragma unroll
        for (int off = 1; off < 64; off <<= 1) sum += __shfl_xor(sum, off);
        float mean = sum * 0.015625f;
        float d = y - mean;
        float vs = d * d;
        #pragma unroll
        for (int off = 1; off < 64; off <<= 1) vs += __shfl_xor(vs, off);
        float var = vs * 0.015625f;
        float o = d * rsqrtf(var + LN_EPS) * ln_scale[lane] + ln_bias[lane];
        out[(size_t)n * 64 + lane] = o;
    }
}

// ---------------------------------------------------------------------------
extern "C" void kernel_launch(void* const* d_in, const int* in_sizes, int n_in,
                              void* d_out, int out_size, void* d_ws, size_t ws_size,
                              hipStream_t stream) {
    const float* nodes     = (const float*)d_in[0];
    const float* edges     = (const float*)d_in[1];
    const int*   receivers = (const int*)d_in[2];
    const int*   senders   = (const int*)d_in[3];
    const float* W         = (const float*)d_in[4];
    const float* W_edge    = (const float*)d_in[5];
    const float* a         = (const float*)d_in[6];
    const float* ln_scale  = (const float*)d_in[7];
    const float* ln_bias   = (const float*)d_in[8];
    float* out = (float*)d_out;

    int N = in_sizes[0] / 64;
    int E = in_sizes[2];
    int NC = (N + 255) / 256;   // coarse buckets of 256 nodes

    char* ws = (char*)d_ws;
    size_t off = 0;
    auto alloc = [&](size_t bytes) -> void* {
        void* p = ws + off;
        off += (bytes + 15) & ~(size_t)15;
        return p;
    };
    __half* Wn_h    = (__half*)alloc((size_t)N * 64 * 2);
    float*  s_s     = (float*)alloc((size_t)N * 4 * 4);
    float*  s_r     = (float*)alloc((size_t)N * 4 * 4);
    float*  lm_self = (float*)alloc((size_t)N * 4 * 4);
    int*    gcursor = (int*)alloc((size_t)NC * 4);
    int4*   slab    = (int4*)alloc((size_t)NC * CAP * 16);
    (void)ws_size; (void)n_in; (void)out_size;

    hipMemsetAsync(gcursor, 0, (size_t)NC * 4, stream);

    node_proj_kernel<<<(N + 3) / 4, 256, 0, stream>>>(
        nodes, W, a, Wn_h, s_s, s_r, lm_self, N);
    edge_sort_kernel<<<(E + BATCH - 1) / BATCH, 256, 0, stream>>>(
        edges, receivers, senders, W_edge, a, s_s, s_r, gcursor, slab, E);
    bucket_accum_kernel<<<NC, 256, 0, stream>>>(
        Wn_h, lm_self, gcursor, slab, ln_scale, ln_bias, out, N);
}

// Round 8
// 449.849 us; speedup vs baseline: 2.3130x; 2.3130x over previous
//
#include <hip/hip_runtime.h>
#include <hip/hip_fp16.h>

#define LEAKY_SLOPE 0.01f
#define LN_EPS 1e-6f

typedef float nfloat4 __attribute__((ext_vector_type(4)));
typedef int   nint4   __attribute__((ext_vector_type(4)));

__device__ __forceinline__ float head_sel(int h, float a, float b, float c, float d) {
    float lo = (h & 1) ? b : a;
    float hi = (h & 1) ? d : c;
    return (h & 2) ? hi : lo;
}

__device__ __forceinline__ float4 nt_load4(const float4* p) {
    nfloat4 v = __builtin_nontemporal_load((const nfloat4*)p);
    return make_float4(v.x, v.y, v.z, v.w);
}
__device__ __forceinline__ int4 nt_loadi4(const int4* p) {
    nint4 v = __builtin_nontemporal_load((const nint4*)p);
    return make_int4(v.x, v.y, v.z, v.w);
}
__device__ __forceinline__ int nt_loadi(const int* p) {
    return __builtin_nontemporal_load(p);
}

// ---------------------------------------------------------------------------
// K1: node projection. One wave per node. Wn stored fp16 (halves downstream
// gather traffic; 6.4 MB table -> L2-friendlier). s_s/s_r/lm_self scalars.
// ---------------------------------------------------------------------------
__global__ __launch_bounds__(256) void node_proj_kernel(
    const float* __restrict__ nodes, const float* __restrict__ W,
    const float* __restrict__ a, __half* __restrict__ Wn_h,
    float* __restrict__ s_s, float* __restrict__ s_r,
    float* __restrict__ lm_self, int N)
{
    __shared__ float Wt[64][65];   // transposed, +1 pad: Wt[i][o] = W[o*64+i]
    int t = threadIdx.x;
    #pragma unroll
    for (int k = 0; k < 16; k++) {
        int flat = k * 256 + t;
        Wt[flat & 63][flat >> 6] = W[flat];
    }
    __syncthreads();
    int lane = t & 63;
    int n = blockIdx.x * 4 + (t >> 6);
    if (n >= N) return;
    float nv = nodes[(size_t)n * 64 + lane];
    float acc = 0.f;
    #pragma unroll
    for (int i = 0; i < 64; i++)
        acc += Wt[i][lane] * __shfl(nv, i);
    Wn_h[(size_t)n * 64 + lane] = __float2half(acc);
    int h = lane >> 4, f = lane & 15;
    float ps = acc * a[h * 48 + f];
    float pr = acc * a[h * 48 + 16 + f];
    #pragma unroll
    for (int off = 1; off < 16; off <<= 1) {
        ps += __shfl_xor(ps, off);
        pr += __shfl_xor(pr, off);
    }
    if (f == 0) {
        s_s[n * 4 + h] = ps;
        s_r[n * 4 + h] = pr;
        float v = ps + pr;
        lm_self[n * 4 + h] = v > 0.f ? v : LEAKY_SLOPE * v;
    }
}

// ---------------------------------------------------------------------------
// K2: histogram of receivers (int4 nt loads -- pure stream)
// ---------------------------------------------------------------------------
__global__ __launch_bounds__(256) void count_kernel(
    const int* __restrict__ receivers, int* __restrict__ counts, int E)
{
    int i = blockIdx.x * 256 + threadIdx.x;
    int base = i * 4;
    if (base + 3 < E) {
        int4 v = nt_loadi4((const int4*)receivers + i);
        atomicAdd(&counts[v.x], 1);
        atomicAdd(&counts[v.y], 1);
        atomicAdd(&counts[v.z], 1);
        atomicAdd(&counts[v.w], 1);
    } else {
        for (int e = base; e < E; e++) atomicAdd(&counts[receivers[e]], 1);
    }
}

// ---------------------------------------------------------------------------
// K3a: per-block partial sums of counts (256 counts per block)
// ---------------------------------------------------------------------------
__global__ __launch_bounds__(256) void partial_sum_kernel(
    const int* __restrict__ counts, int* __restrict__ partials, int N)
{
    __shared__ int sh[4];
    int i = blockIdx.x * 256 + threadIdx.x;
    int v = (i < N) ? counts[i] : 0;
    #pragma unroll
    for (int off = 1; off < 64; off <<= 1) v += __shfl_xor(v, off);
    int lane = threadIdx.x & 63, wv = threadIdx.x >> 6;
    if (lane == 0) sh[wv] = v;
    __syncthreads();
    if (threadIdx.x == 0) partials[blockIdx.x] = sh[0] + sh[1] + sh[2] + sh[3];
}

// ---------------------------------------------------------------------------
// K3b: single tiny block: exclusive scan of the partials; row_ptr[N] = E.
// ---------------------------------------------------------------------------
__global__ __launch_bounds__(256) void scan_partials_kernel(
    int* __restrict__ partials, int B, int* __restrict__ row_ptr, int N, int E)
{
    __shared__ int sh[256];
    __shared__ int carry;
    int t = threadIdx.x;
    if (t == 0) carry = 0;
    __syncthreads();
    for (int base = 0; base < B; base += 256) {
        int idx = base + t;
        int v = (idx < B) ? partials[idx] : 0;
        sh[t] = v;
        __syncthreads();
        for (int off = 1; off < 256; off <<= 1) {
            int u = (t >= off) ? sh[t - off] : 0;
            __syncthreads();
            sh[t] += u;
            __syncthreads();
        }
        int incl = sh[t];
        int c = carry;
        if (idx < B) partials[idx] = c + incl - v;   // exclusive
        __syncthreads();
        if (t == 255) carry = c + incl;
        __syncthreads();
    }
    if (t == 0) row_ptr[N] = E;
}

// ---------------------------------------------------------------------------
// K3c: per-block exclusive scan of counts + block offset -> row_ptr, cursor
// ---------------------------------------------------------------------------
__global__ __launch_bounds__(256) void scan_apply_kernel(
    const int* __restrict__ counts, const int* __restrict__ partials,
    int* __restrict__ row_ptr, int* __restrict__ cursor, int N)
{
    __shared__ int sh[256];
    int t = threadIdx.x;
    int i = blockIdx.x * 256 + t;
    int v = (i < N) ? counts[i] : 0;
    sh[t] = v;
    __syncthreads();
    for (int off = 1; off < 256; off <<= 1) {
        int u = (t >= off) ? sh[t - off] : 0;
        __syncthreads();
        sh[t] += u;
        __syncthreads();
    }
    int excl = sh[t] - v + partials[blockIdx.x];
    if (i < N) {
        row_ptr[i] = excl;
        cursor[i] = excl;
    }
}

// ---------------------------------------------------------------------------
// K4: per-edge logits + scatter into CSR slots. NT loads on the 102 MB edge
// stream so the scatter frontier + s_s/s_r tables stay L2-resident.
// Payload 16B: {lm0 f32, lm1 f32, (lm2 h | lm3 h<<16), (sender u16 | spare)}
// ---------------------------------------------------------------------------
__global__ __launch_bounds__(256) void edge_kernel(
    const float* __restrict__ edges, const int* __restrict__ receivers,
    const int* __restrict__ senders, const float* __restrict__ W_edge,
    const float* __restrict__ a, const float* __restrict__ s_s,
    const float* __restrict__ s_r, int* __restrict__ cursor,
    int4* __restrict__ sorted, int E)
{
    __shared__ float be[4][16];   // be[h][i] = sum_f W_edge[h,f,i]*a_e[h,f]
    int t = threadIdx.x;
    if (t < 64) {
        int h = t >> 4, i = t & 15;
        float s = 0.f;
        #pragma unroll
        for (int f = 0; f < 16; f++)
            s += W_edge[(h * 16 + f) * 16 + i] * a[h * 48 + 32 + f];
        be[h][i] = s;
    }
    __syncthreads();
    int e = blockIdx.x * 256 + t;
    if (e >= E) return;
    int r = nt_loadi(receivers + e);
    int s = nt_loadi(senders + e);
    const float4* ef = (const float4*)(edges + (size_t)e * 16);
    float4 e0 = nt_load4(ef + 0), e1 = nt_load4(ef + 1);
    float4 e2 = nt_load4(ef + 2), e3 = nt_load4(ef + 3);
    float4 ssv = ((const float4*)s_s)[s];
    float4 srv = ((const float4*)s_r)[r];
    float ev[16] = {e0.x, e0.y, e0.z, e0.w, e1.x, e1.y, e1.z, e1.w,
                    e2.x, e2.y, e2.z, e2.w, e3.x, e3.y, e3.z, e3.w};
    float ssa[4] = {ssv.x, ssv.y, ssv.z, ssv.w};
    float sra[4] = {srv.x, srv.y, srv.z, srv.w};
    float lm[4];
    #pragma unroll
    for (int hh = 0; hh < 4; hh++) {
        float se = 0.f;
        #pragma unroll
        for (int i = 0; i < 16; i++) se += be[hh][i] * ev[i];
        float v = ssa[hh] + sra[hh] + se;
        lm[hh] = v > 0.f ? v : LEAKY_SLOPE * v;
    }
    int pos = atomicAdd(&cursor[r], 1);
    unsigned packA = (unsigned)__half_as_ushort(__float2half(lm[2])) |
                     ((unsigned)__half_as_ushort(__float2half(lm[3])) << 16);
    sorted[pos] = make_int4(__float_as_int(lm[0]), __float_as_int(lm[1]),
                            (int)packA, (int)(unsigned)s);
}

// ---------------------------------------------------------------------------
// K5: single-pass per-node softmax (no max-shift) + aggregation + ELU + LN.
// One wave per node, lane = h*16+f owns one output feature. LDS-staged chunks,
// no barriers (wave-private LDS regions). NT load on the sorted stream; fp16
// Wn gathers (128 B/wave coalesced) keep the table L2-hot.
// ---------------------------------------------------------------------------
__global__ __launch_bounds__(256) void node_aggr_kernel(
    const __half* __restrict__ Wn_h, const float* __restrict__ lm_self,
    const int* __restrict__ row_ptr, const int4* __restrict__ sorted,
    const float* __restrict__ ln_scale, const float* __restrict__ ln_bias,
    float* __restrict__ out, int N)
{
    __shared__ float lds_w[4][64][4];
    __shared__ int   lds_s[4][64];
    int t = threadIdx.x;
    int lane = t & 63;
    int wv = t >> 6;
    int n = blockIdx.x * 4 + wv;
    if (n >= N) return;
    int beg = row_ptr[n], end = row_ptr[n + 1];
    int cntn = end - beg;
    int h = lane >> 4;

    float acc = 0.f, acc2 = 0.f;
    float p0 = 0.f, p1 = 0.f, p2 = 0.f, p3 = 0.f;  // partial softmax denoms

    for (int base = 0; base < cntn; base += 64) {
        int j = base + lane;
        float w0 = 0.f, w1 = 0.f, w2 = 0.f, w3 = 0.f;
        int sv = 0;
        if (j < cntn) {
            int4 pl = nt_loadi4(sorted + beg + j);
            w0 = __expf(__int_as_float(pl.x));
            w1 = __expf(__int_as_float(pl.y));
            unsigned pa = (unsigned)pl.z;
            w2 = __expf(__half2float(__ushort_as_half((unsigned short)(pa & 0xFFFFu))));
            w3 = __expf(__half2float(__ushort_as_half((unsigned short)(pa >> 16))));
            sv = pl.w;
        }
        p0 += w0; p1 += w1; p2 += w2; p3 += w3;
        lds_s[wv][lane] = sv;
        *(float4*)&lds_w[wv][lane][0] = make_float4(w0, w1, w2, w3);
        int cnt = min(64, cntn - base);
        int k = 0;
        for (; k + 1 < cnt; k += 2) {
            int   sk0 = lds_s[wv][k];
            int   sk1 = lds_s[wv][k + 1];
            float a0  = lds_w[wv][k][h];
            float a1  = lds_w[wv][k + 1][h];
            float v0 = __half2float(Wn_h[(size_t)sk0 * 64 + lane]);
            float v1 = __half2float(Wn_h[(size_t)sk1 * 64 + lane]);
            acc  += a0 * v0;
            acc2 += a1 * v1;
        }
        if (k < cnt)
            acc += lds_w[wv][k][h] * __half2float(Wn_h[(size_t)lds_s[wv][k] * 64 + lane]);
    }
    acc += acc2;

    // reduce softmax denominators across the wave
    #pragma unroll
    for (int off = 1; off < 64; off <<= 1) {
        p0 += __shfl_xor(p0, off);
        p1 += __shfl_xor(p1, off);
        p2 += __shfl_xor(p2, off);
        p3 += __shfl_xor(p3, off);
    }
    // self edge
    float4 ls = ((const float4*)lm_self)[n];
    float ws0 = __expf(ls.x), ws1 = __expf(ls.y);
    float ws2 = __expf(ls.z), ws3 = __expf(ls.w);
    float totd  = head_sel(h, p0 + ws0, p1 + ws1, p2 + ws2, p3 + ws3);
    float wself = head_sel(h, ws0, ws1, ws2, ws3);
    float selfv = __half2float(Wn_h[(size_t)n * 64 + lane]);
    acc = (acc + wself * selfv) / totd;

    // ---- ELU + LayerNorm over the 64 features (= 64 lanes) ----
    float y = acc > 0.f ? acc : expm1f(acc);
    float sum = y;
    #pragma unroll
    for (int off = 1; off < 64; off <<= 1) sum += __shfl_xor(sum, off);
    float mean = sum * 0.015625f;
    float d = y - mean;
    float vs = d * d;
    #pragma unroll
    for (int off = 1; off < 64; off <<= 1) vs += __shfl_xor(vs, off);
    float var = vs * 0.015625f;
    float o = d * rsqrtf(var + LN_EPS) * ln_scale[lane] + ln_bias[lane];
    out[(size_t)n * 64 + lane] = o;
}

// ---------------------------------------------------------------------------
extern "C" void kernel_launch(void* const* d_in, const int* in_sizes, int n_in,
                              void* d_out, int out_size, void* d_ws, size_t ws_size,
                              hipStream_t stream) {
    const float* nodes     = (const float*)d_in[0];
    const float* edges     = (const float*)d_in[1];
    const int*   receivers = (const int*)d_in[2];
    const int*   senders   = (const int*)d_in[3];
    const float* W         = (const float*)d_in[4];
    const float* W_edge    = (const float*)d_in[5];
    const float* a         = (const float*)d_in[6];
    const float* ln_scale  = (const float*)d_in[7];
    const float* ln_bias   = (const float*)d_in[8];
    float* out = (float*)d_out;

    int N = in_sizes[0] / 64;
    int E = in_sizes[2];
    int B = (N + 255) / 256;   // scan blocks

    char* ws = (char*)d_ws;
    size_t off = 0;
    auto alloc = [&](size_t bytes) -> void* {
        void* p = ws + off;
        off += (bytes + 15) & ~(size_t)15;
        return p;
    };
    __half* Wn_h    = (__half*)alloc((size_t)N * 64 * 2);
    float*  s_s     = (float*)alloc((size_t)N * 4 * 4);
    float*  s_r     = (float*)alloc((size_t)N * 4 * 4);
    float*  lm_self = (float*)alloc((size_t)N * 4 * 4);
    int*    counts  = (int*)alloc((size_t)N * 4);
    int*    row_ptr = (int*)alloc((size_t)(N + 1) * 4);
    int*    cursor  = (int*)alloc((size_t)N * 4);
    int*    partials= (int*)alloc((size_t)B * 4);
    int4*   sorted  = (int4*)alloc((size_t)E * 16);
    (void)ws_size; (void)n_in; (void)out_size;

    (void)hipMemsetAsync(counts, 0, (size_t)N * 4, stream);

    node_proj_kernel<<<(N + 3) / 4, 256, 0, stream>>>(
        nodes, W, a, Wn_h, s_s, s_r, lm_self, N);
    count_kernel<<<(E / 4 + 255) / 256, 256, 0, stream>>>(receivers, counts, E);
    partial_sum_kernel<<<B, 256, 0, stream>>>(counts, partials, N);
    scan_partials_kernel<<<1, 256, 0, stream>>>(partials, B, row_ptr, N, E);
    scan_apply_kernel<<<B, 256, 0, stream>>>(counts, partials, row_ptr, cursor, N);
    edge_kernel<<<(E + 255) / 256, 256, 0, stream>>>(
        edges, receivers, senders, W_edge, a, s_s, s_r, cursor, sorted, E);
    node_aggr_kernel<<<(N + 3) / 4, 256, 0, stream>>>(
        Wn_h, lm_self, row_ptr, sorted, ln_scale, ln_bias, out, N);
}